// Round 1
// baseline (1223.995 us; speedup 1.0000x reference)
//
#include <hip/hip_runtime.h>
#include <hip/hip_bf16.h>
#include <stdint.h>

typedef unsigned short u16;
typedef __bf16 bf16x8 __attribute__((ext_vector_type(8)));
typedef float f32x4 __attribute__((ext_vector_type(4)));

struct __align__(8) us4 { u16 x, y, z, w; };

// round-to-nearest-even fp32 -> bf16
__device__ __forceinline__ u16 f2b(float f){
  uint32_t u = __float_as_uint(f);
  u = (u + 0x7fffu + ((u >> 16) & 1u)) >> 16;
  return (u16)u;
}

typedef const void __attribute__((address_space(1))) gv_t;
typedef void __attribute__((address_space(3))) sv_t;

__device__ __forceinline__ void gload16(const void* g, void* l){
  __builtin_amdgcn_global_load_lds((gv_t*)g, (sv_t*)l, 16, 0, 0);
}

// ---------------- elementwise mask * cast ----------------
// in: fp32 [rows, 512], msk: int [rows]; out bf16. 128 quads per row.
__global__ void mask_cast_k(const float4* __restrict__ in, const int* __restrict__ msk,
                            us4* __restrict__ out, int nquads){
  for (int i = blockIdx.x*blockDim.x + threadIdx.x; i < nquads; i += gridDim.x*blockDim.x){
    float4 v = in[i];
    int row = i >> 7;
    if (msk[row] == 0){ v.x = 0.f; v.y = 0.f; v.z = 0.f; v.w = 0.f; }
    us4 o; o.x = f2b(v.x); o.y = f2b(v.y); o.z = f2b(v.z); o.w = f2b(v.w);
    out[i] = o;
  }
}

// ---------------- weight transpose fp32 [R,C] -> bf16 [C,R] ----------------
__global__ void wtrans_k(const float* __restrict__ W, u16* __restrict__ out, int R, int C){
  __shared__ float tile[32][33];
  int c0 = blockIdx.x*32, r0 = blockIdx.y*32;
  int tx = threadIdx.x & 31, ty = threadIdx.x >> 5;   // 8 rows per pass
  #pragma unroll
  for (int i = 0; i < 4; ++i){
    int rr = ty + i*8;
    tile[rr][tx] = W[(long)(r0+rr)*C + c0 + tx];
  }
  __syncthreads();
  #pragma unroll
  for (int i = 0; i < 4; ++i){
    int rr = ty + i*8;
    out[(long)(c0+rr)*R + r0 + tx] = f2b(tile[tx][rr]);
  }
}

// ---------------- batched bf16 transpose [Bb,R,C] -> [Bb,C,R] ----------------
__global__ void btrans_k(const u16* __restrict__ in, u16* __restrict__ out, int R, int C){
  __shared__ u16 tile[64][65];
  long boff = (long)blockIdx.z * R * C;
  int c0 = blockIdx.x*64, r0 = blockIdx.y*64;
  int t = threadIdx.x;
  #pragma unroll
  for (int i = 0; i < 16; ++i){
    int idx = t + i*256; int rr = idx >> 6, cc = idx & 63;
    tile[rr][cc] = in[boff + (long)(r0+rr)*C + c0 + cc];
  }
  __syncthreads();
  #pragma unroll
  for (int i = 0; i < 16; ++i){
    int idx = t + i*256; int rr = idx >> 6, cc = idx & 63;
    out[boff + (long)(c0+rr)*R + r0 + cc] = tile[cc][rr];
  }
}

// ---------------- NT bf16 MFMA GEMM ----------------
// C[M,N] = A[M,K] @ Bt[N,K]^T, batched via blockIdx.z. 128x128 tile, BK=32,
// 256 thr = 4 waves (2x2), each wave 64x64 via 4x4 frags of 16x16x32.
// MODE 0: store bf16 (opt relu). MODE 1: store f32. MODE 2: relu + column-sum
// atomics into f32 agg[m0/Lrows][N] (fuses compared.sum(axis=1)).
// SPLIT: A is the concat [A0 (K<KA0) | A1] along K.
template<int MODE, bool RELU, bool SPLIT>
__global__ __launch_bounds__(256) void gemm_nt(
    const u16* __restrict__ A0, const u16* __restrict__ A1, int KA0, int lda0, int lda1,
    const u16* __restrict__ Bt, void* __restrict__ Cout,
    int N, int K, long sAb, long sBb, long sCb, int Lrows)
{
  __shared__ u16 As[128*32];
  __shared__ u16 Bs[128*32];
  __shared__ float colsum[128];
  const int bz = blockIdx.z;
  const u16* a0 = A0 + (long)bz*sAb;
  const u16* a1 = SPLIT ? (A1 + (long)bz*sAb) : (const u16*)nullptr;
  const u16* bt = Bt + (long)bz*sBb;
  const int m0 = blockIdx.y*128, n0 = blockIdx.x*128;
  const int t = threadIdx.x, lane = t & 63, wv = t >> 6;
  const int wm = wv >> 1, wn = wv & 1, r = lane & 15, q = lane >> 4;

  f32x4 acc[4][4] = {};

  for (int k0 = 0; k0 < K; k0 += 32){
    #pragma unroll
    for (int i = 0; i < 2; ++i){
      int idx = t + i*256;
      int row = idx >> 2, ks = k0 + (idx & 3)*8;
      const u16* src;
      if (SPLIT && ks >= KA0) src = a1 + (long)(m0+row)*lda1 + (ks - KA0);
      else                    src = a0 + (long)(m0+row)*lda0 + ks;
      gload16(src, &As[idx*8]);
    }
    #pragma unroll
    for (int i = 0; i < 2; ++i){
      int idx = t + i*256;
      int row = idx >> 2, ks = k0 + (idx & 3)*8;
      gload16(bt + (long)(n0+row)*K + ks, &Bs[idx*8]);
    }
    __syncthreads();   // compiler drains vmcnt before s_barrier
    bf16x8 af[4], bfr[4];
    #pragma unroll
    for (int mi = 0; mi < 4; ++mi)
      af[mi] = *reinterpret_cast<const bf16x8*>(&As[(wm*64 + mi*16 + r)*32 + q*8]);
    #pragma unroll
    for (int ni = 0; ni < 4; ++ni)
      bfr[ni] = *reinterpret_cast<const bf16x8*>(&Bs[(wn*64 + ni*16 + r)*32 + q*8]);
    #pragma unroll
    for (int mi = 0; mi < 4; ++mi)
      #pragma unroll
      for (int ni = 0; ni < 4; ++ni)
        acc[mi][ni] = __builtin_amdgcn_mfma_f32_16x16x32_bf16(af[mi], bfr[ni], acc[mi][ni], 0, 0, 0);
    __syncthreads();
  }

  if constexpr (MODE == 2){
    if (t < 128) colsum[t] = 0.f;
    __syncthreads();
    #pragma unroll
    for (int ni = 0; ni < 4; ++ni){
      float v = 0.f;
      #pragma unroll
      for (int mi = 0; mi < 4; ++mi)
        #pragma unroll
        for (int i = 0; i < 4; ++i) v += fmaxf(acc[mi][ni][i], 0.f);
      v += __shfl_xor(v, 16);
      v += __shfl_xor(v, 32);
      if (q == 0) atomicAdd(&colsum[wn*64 + ni*16 + r], v);
    }
    __syncthreads();
    float* agg = (float*)Cout;
    if (t < 128) atomicAdd(&agg[(long)(m0 / Lrows)*N + n0 + t], colsum[t]);
  } else {
    #pragma unroll
    for (int mi = 0; mi < 4; ++mi){
      #pragma unroll
      for (int ni = 0; ni < 4; ++ni){
        int rr = m0 + wm*64 + mi*16 + q*4;
        int cc = n0 + wn*64 + ni*16 + r;
        #pragma unroll
        for (int i = 0; i < 4; ++i){
          float v = acc[mi][ni][i];
          if (RELU) v = fmaxf(v, 0.f);
          if constexpr (MODE == 0)
            ((u16*)Cout)[(long)bz*sCb + (long)(rr+i)*N + cc] = f2b(v);
          else
            ((float*)Cout)[(long)bz*sCb + (long)(rr+i)*N + cc] = v;
        }
      }
    }
  }
}

// ---------------- flat masked softmax (online, 2-stage) ----------------
// stage 1: 8 chunks x 128 batches, each block -> partial (max, sumexp)
__global__ __launch_bounds__(256) void sm_partial(const float* __restrict__ att,
    const int* __restrict__ pm, const int* __restrict__ hm, float2* __restrict__ part)
{
  int b = blockIdx.y, ch = blockIdx.x;
  const float* a = att + (long)b*262144 + (long)ch*32768;
  __shared__ unsigned char pmk[64], hmk[512];
  __shared__ float2 wred[4];
  int t = threadIdx.x;
  if (t < 64) pmk[t] = (unsigned char)pm[b*512 + ch*64 + t];
  for (int i = t; i < 512; i += 256) hmk[i] = (unsigned char)hm[b*512 + i];
  __syncthreads();
  float m = -3.0e38f, s = 0.f;
  for (int i = t; i < 32768; i += 256){
    float l = a[i];
    if (!(pmk[i >> 9] & hmk[i & 511])) l = -1.0e9f;
    float nm = fmaxf(m, l);
    s = s*__expf(m - nm) + __expf(l - nm);
    m = nm;
  }
  #pragma unroll
  for (int d = 1; d < 64; d <<= 1){
    float om = __shfl_xor(m, d), os = __shfl_xor(s, d);
    float nm = fmaxf(m, om);
    s = s*__expf(m - nm) + os*__expf(om - nm);
    m = nm;
  }
  if ((t & 63) == 0) wred[t >> 6] = float2{m, s};
  __syncthreads();
  if (t == 0){
    m = wred[0].x; s = wred[0].y;
    for (int w = 1; w < 4; ++w){
      float om = wred[w].x, os = wred[w].y, nm = fmaxf(m, om);
      s = s*__expf(m - nm) + os*__expf(om - nm); m = nm;
    }
    part[b*8 + ch] = float2{m, s};
  }
}

__global__ void sm_merge(const float2* __restrict__ part, float2* __restrict__ bms){
  int b = threadIdx.x;   // 128 threads
  float m = -3.0e38f, s = 0.f;
  for (int i = 0; i < 8; ++i){
    float2 p = part[b*8 + i];
    float nm = fmaxf(m, p.x);
    s = s*__expf(m - nm) + p.y*__expf(p.x - nm);
    m = nm;
  }
  bms[b] = float2{m, 1.0f / s};
}

// stage 2: write bf16 probabilities (masked -> exact 0, matching fp32 underflow)
__global__ void sm_write(const float4* __restrict__ att, const int* __restrict__ pm,
    const int* __restrict__ hm, const float2* __restrict__ bms, us4* __restrict__ p2h)
{
  const int total = 128*65536;
  for (int i = blockIdx.x*blockDim.x + threadIdx.x; i < total; i += gridDim.x*blockDim.x){
    int b = i >> 16, rem = i & 65535, p = rem >> 7, h4 = (rem & 127) << 2;
    float2 ms = bms[b];
    float4 v = att[i];
    int pv = pm[b*512 + p];
    const int* hmb = hm + b*512 + h4;
    us4 o;
    o.x = (pv && hmb[0]) ? f2b(__expf(v.x - ms.x)*ms.y) : (u16)0;
    o.y = (pv && hmb[1]) ? f2b(__expf(v.y - ms.x)*ms.y) : (u16)0;
    o.z = (pv && hmb[2]) ? f2b(__expf(v.z - ms.x)*ms.y) : (u16)0;
    o.w = (pv && hmb[3]) ? f2b(__expf(v.w - ms.x)*ms.y) : (u16)0;
    p2h[i] = o;
  }
}

// ---------------- fused aggregate FF + scorer + softmax (per batch row) ----------------
__global__ __launch_bounds__(256) void final_ff(const float* __restrict__ aggP,
    const float* __restrict__ aggH, const float* __restrict__ g0,
    const float* __restrict__ g1, const float* __restrict__ sc, float* __restrict__ out)
{
  int b = blockIdx.x, t = threadIdx.x;
  __shared__ float x[1024];
  __shared__ float tt[512];
  __shared__ float2 wred[4];
  for (int i = t; i < 512; i += 256){ x[i] = aggP[b*512 + i]; x[512 + i] = aggH[b*512 + i]; }
  __syncthreads();
  for (int j = t; j < 512; j += 256){
    float a = 0.f;
    for (int k = 0; k < 1024; ++k) a += x[k]*g0[k*512 + j];
    tt[j] = fmaxf(a, 0.f);
  }
  __syncthreads();
  for (int j = t; j < 512; j += 256){
    float a = 0.f;
    for (int k = 0; k < 512; ++k) a += tt[k]*g1[k*512 + j];
    x[j] = fmaxf(a, 0.f);
  }
  __syncthreads();
  float s0 = 0.f, s1 = 0.f;
  for (int k = t; k < 512; k += 256){ s0 += x[k]*sc[2*k]; s1 += x[k]*sc[2*k + 1]; }
  #pragma unroll
  for (int d = 1; d < 64; d <<= 1){ s0 += __shfl_xor(s0, d); s1 += __shfl_xor(s1, d); }
  if ((t & 63) == 0) wred[t >> 6] = float2{s0, s1};
  __syncthreads();
  if (t == 0){
    s0 = wred[0].x + wred[1].x + wred[2].x + wred[3].x;
    s1 = wred[0].y + wred[1].y + wred[2].y + wred[3].y;
    float mm = fmaxf(s0, s1);
    float e0 = __expf(s0 - mm), e1 = __expf(s1 - mm);
    float inv = 1.f / (e0 + e1);
    out[2*b]     = e0*inv;
    out[2*b + 1] = e1*inv;
  }
}

// =============================== launcher ===============================
extern "C" void kernel_launch(void* const* d_in, const int* in_sizes, int n_in,
                              void* d_out, int out_size, void* d_ws, size_t ws_size,
                              hipStream_t stream) {
  const float* premise    = (const float*)d_in[0];
  const float* hypothesis = (const float*)d_in[1];
  const int*   pm         = (const int*)d_in[2];
  const int*   hm         = (const int*)d_in[3];
  const float* w_a0       = (const float*)d_in[4];
  const float* w_a1       = (const float*)d_in[5];
  const float* w_c0       = (const float*)d_in[6];
  const float* w_c1       = (const float*)d_in[7];
  const float* w_g0       = (const float*)d_in[8];
  const float* w_g1       = (const float*)d_in[9];
  const float* w_sc       = (const float*)d_in[10];
  float* out = (float*)d_out;

  const size_t MB = 1ull << 20;
  if (ws_size < 456*MB) return;   // need ~454 MB; clean fail if undersized

  char* ws = (char*)d_ws;
  u16*  p_emb  = (u16*)(ws + 0);        // [B,L,D] bf16, masked premise
  u16*  h_emb  = (u16*)(ws + 64*MB);    // [B,L,D]
  u16*  bufC   = (u16*)(ws + 128*MB);   // t0 / p2h_b / cmp_t
  u16*  bufD   = (u16*)(ws + 192*MB);   // proj_p / h2p_b
  u16*  bufE   = (u16*)(ws + 256*MB);   // proj_h / h_embT / h2p_align
  float* att   = (float*)(ws + 320*MB); // [B,P,H] f32 (dies after softmax)
  u16*  p_embT = (u16*)(ws + 320*MB);   // reuses att region
  u16*  p2h_al = (u16*)(ws + 384*MB);
  u16*  wt_a0  = (u16*)(ws + 448*MB);
  u16*  wt_a1  = (u16*)(ws + 449*MB);
  u16*  wt_c0  = (u16*)(ws + 450*MB);   // [512,1024] bf16 (1 MB)
  u16*  wt_c1  = (u16*)(ws + 452*MB);
  float* aggP  = (float*)(ws + 453*MB);
  float* aggH  = (float*)(ws + 453*MB + 256*1024);
  float2* part = (float2*)(ws + 453*MB + 512*1024);
  float2* bms  = (float2*)(ws + 453*MB + 520*1024);

  const long S = 262144;       // 512*512 per-batch matrix elements
  const int NQ = 8388608;      // 128*512*512/4 quads

  // 1. mask + cast to bf16
  mask_cast_k<<<2048, 256, 0, stream>>>((const float4*)premise, pm, (us4*)p_emb, NQ);
  mask_cast_k<<<2048, 256, 0, stream>>>((const float4*)hypothesis, hm, (us4*)h_emb, NQ);

  // 2. weight transposes (fp32 -> bf16, [N,K] form for NT GEMM)
  wtrans_k<<<dim3(16,16), 256, 0, stream>>>(w_a0, wt_a0, 512, 512);
  wtrans_k<<<dim3(16,16), 256, 0, stream>>>(w_a1, wt_a1, 512, 512);
  wtrans_k<<<dim3(16,32), 256, 0, stream>>>(w_c0, wt_c0, 1024, 512);
  wtrans_k<<<dim3(16,16), 256, 0, stream>>>(w_c1, wt_c1, 512, 512);

  // 3. attend FF: proj = relu(relu(emb@a0)@a1)
  gemm_nt<0,true,false><<<dim3(4,512,1), 256, 0, stream>>>(p_emb, nullptr, 0, 512, 0, wt_a0, bufC, 512, 512, 0,0,0, 0);
  gemm_nt<0,true,false><<<dim3(4,512,1), 256, 0, stream>>>(bufC,  nullptr, 0, 512, 0, wt_a1, bufD, 512, 512, 0,0,0, 0);
  gemm_nt<0,true,false><<<dim3(4,512,1), 256, 0, stream>>>(h_emb, nullptr, 0, 512, 0, wt_a0, bufC, 512, 512, 0,0,0, 0);
  gemm_nt<0,true,false><<<dim3(4,512,1), 256, 0, stream>>>(bufC,  nullptr, 0, 512, 0, wt_a1, bufE, 512, 512, 0,0,0, 0);

  // 4. att[b] = proj_p[b] @ proj_h[b]^T  (proj_h already in [N,K] form)
  gemm_nt<1,false,false><<<dim3(4,4,128), 256, 0, stream>>>(bufD, nullptr, 0, 512, 0, bufE, att, 512, 512, S, S, S, 0);

  // 5. h_embT for the p2h_align GEMM (proj_h no longer needed)
  btrans_k<<<dim3(8,8,128), 256, 0, stream>>>(h_emb, bufE, 512, 512);

  // 6. flat masked softmax over P*H per batch
  sm_partial<<<dim3(8,128), 256, 0, stream>>>(att, pm, hm, part);
  sm_merge<<<1, 128, 0, stream>>>(part, bms);
  sm_write<<<2048, 256, 0, stream>>>((const float4*)att, pm, hm, bms, (us4*)bufC); // p2h bf16

  // 7. h2p = p2h^T (same softmax stats: flattened-axis softmax is transpose-invariant)
  btrans_k<<<dim3(8,8,128), 256, 0, stream>>>(bufC, bufD, 512, 512);
  btrans_k<<<dim3(8,8,128), 256, 0, stream>>>(p_emb, p_embT, 512, 512);   // att region dead now

  // 8. alignments
  gemm_nt<0,false,false><<<dim3(4,4,128), 256, 0, stream>>>(bufC, nullptr, 0, 512, 0, bufE,   p2h_al, 512, 512, S, S, S, 0);
  gemm_nt<0,false,false><<<dim3(4,4,128), 256, 0, stream>>>(bufD, nullptr, 0, 512, 0, p_embT, bufE,   512, 512, S, S, S, 0);

  // 9. compare_p: relu(concat[p_emb, p2h_al] @ c0) -> then layer2+relu+col-sum
  gemm_nt<0,true,true><<<dim3(4,512,1), 256, 0, stream>>>(p_emb, p2h_al, 512, 512, 512, wt_c0, bufC, 512, 1024, 0,0,0, 0);
  hipMemsetAsync(aggP, 0, 128*512*sizeof(float), stream);
  gemm_nt<2,true,false><<<dim3(4,512,1), 256, 0, stream>>>(bufC, nullptr, 0, 512, 0, wt_c1, aggP, 512, 512, 0,0,0, 512);

  // 10. compare_h
  gemm_nt<0,true,true><<<dim3(4,512,1), 256, 0, stream>>>(h_emb, bufE, 512, 512, 512, wt_c0, bufC, 512, 1024, 0,0,0, 0);
  hipMemsetAsync(aggH, 0, 128*512*sizeof(float), stream);
  gemm_nt<2,true,false><<<dim3(4,512,1), 256, 0, stream>>>(bufC, nullptr, 0, 512, 0, wt_c1, aggH, 512, 512, 0,0,0, 512);

  // 11. aggregate FF + scorer + 2-class softmax (fp32)
  final_ff<<<128, 256, 0, stream>>>(aggP, aggH, w_g0, w_g1, w_sc, out);
}

// Round 2
// 1068.342 us; speedup vs baseline: 1.1457x; 1.1457x over previous
//
#include <hip/hip_runtime.h>
#include <hip/hip_bf16.h>
#include <stdint.h>

typedef unsigned short u16;
typedef __bf16 bf16x8 __attribute__((ext_vector_type(8)));
typedef float f32x4 __attribute__((ext_vector_type(4)));

struct __align__(8) us4 { u16 x, y, z, w; };

// round-to-nearest-even fp32 -> bf16
__device__ __forceinline__ u16 f2b(float f){
  uint32_t u = __float_as_uint(f);
  u = (u + 0x7fffu + ((u >> 16) & 1u)) >> 16;
  return (u16)u;
}
__device__ __forceinline__ float b2f(u16 u){
  return __uint_as_float(((uint32_t)u) << 16);
}

typedef const void __attribute__((address_space(1))) gv_t;
typedef void __attribute__((address_space(3))) sv_t;

__device__ __forceinline__ void gload16(const void* g, void* l){
  __builtin_amdgcn_global_load_lds((gv_t*)g, (sv_t*)l, 16, 0, 0);
}

// ---------------- elementwise mask * cast ----------------
__global__ void mask_cast_k(const float4* __restrict__ in, const int* __restrict__ msk,
                            us4* __restrict__ out, int nquads){
  for (int i = blockIdx.x*blockDim.x + threadIdx.x; i < nquads; i += gridDim.x*blockDim.x){
    float4 v = in[i];
    int row = i >> 7;
    if (msk[row] == 0){ v.x = 0.f; v.y = 0.f; v.z = 0.f; v.w = 0.f; }
    us4 o; o.x = f2b(v.x); o.y = f2b(v.y); o.z = f2b(v.z); o.w = f2b(v.w);
    out[i] = o;
  }
}

// ---------------- weight transpose fp32 [R,C] -> bf16 [C,R] ----------------
__global__ void wtrans_k(const float* __restrict__ W, u16* __restrict__ out, int R, int C){
  __shared__ float tile[32][33];
  int c0 = blockIdx.x*32, r0 = blockIdx.y*32;
  int tx = threadIdx.x & 31, ty = threadIdx.x >> 5;
  #pragma unroll
  for (int i = 0; i < 4; ++i){
    int rr = ty + i*8;
    tile[rr][tx] = W[(long)(r0+rr)*C + c0 + tx];
  }
  __syncthreads();
  #pragma unroll
  for (int i = 0; i < 4; ++i){
    int rr = ty + i*8;
    out[(long)(c0+rr)*R + r0 + tx] = f2b(tile[tx][rr]);
  }
}

// ---------------- batched bf16 transpose [Bb,R,C] -> [Bb,C,R] ----------------
__global__ void btrans_k(const u16* __restrict__ in, u16* __restrict__ out, int R, int C){
  __shared__ u16 tile[64][65];
  long boff = (long)blockIdx.z * R * C;
  int c0 = blockIdx.x*64, r0 = blockIdx.y*64;
  int t = threadIdx.x;
  #pragma unroll
  for (int i = 0; i < 16; ++i){
    int idx = t + i*256; int rr = idx >> 6, cc = idx & 63;
    tile[rr][cc] = in[boff + (long)(r0+rr)*C + c0 + cc];
  }
  __syncthreads();
  #pragma unroll
  for (int i = 0; i < 16; ++i){
    int idx = t + i*256; int rr = idx >> 6, cc = idx & 63;
    out[boff + (long)(c0+rr)*R + r0 + cc] = tile[cc][rr];
  }
}

// ---------------- NT bf16 MFMA GEMM, double-buffered + swizzled ----------------
// C[M,N] = A[M,K] @ Bt[N,K]^T, 128x128 tile, BK=32, 256 thr = 4 waves (2x2).
// Grid is 1-D nwg=2048, XCD-remapped: l=(p%8)*256+p/8; bx=l&3 (N-tile),
// by=(l>>2)&gyMask (M-tile), bz=(l>>2)>>gyShift (batch).
// LDS layout: 16B chunks, chunk(row,q) at index row*4 + (q ^ ((row>>1)&3)).
// MODE 0: store bf16 (opt relu). MODE 2: relu + column-sum atomics (fused
// compared.sum). MODE 3: store bf16 + per-block masked softmax partials.
// SPLIT: A is concat [A0 | A1] along K at KA0.
template<int MODE, bool RELU, bool SPLIT>
__global__ __launch_bounds__(256) void gemm_nt(
    const u16* __restrict__ A0, const u16* __restrict__ A1, int KA0, int lda0, int lda1,
    const u16* __restrict__ Bt, void* __restrict__ Cout,
    const int* __restrict__ pm, const int* __restrict__ hm, float2* __restrict__ part,
    int N, int K, long sAb, long sBb, long sCb, int Lrows,
    int gyMask, int gyShift)
{
  __shared__ u16 As[2][128*32];
  __shared__ u16 Bs[2][128*32];
  __shared__ float redbuf[128];
  __shared__ float2 wred4[4];

  const int p = blockIdx.x;
  const int l = ((p & 7) << 8) | (p >> 3);     // nwg=2048 bijective XCD remap
  const int bx = l & 3;
  const int rest = l >> 2;
  const int by = rest & gyMask;
  const int bz = rest >> gyShift;

  const u16* a0 = A0 + (long)bz*sAb;
  const u16* a1 = SPLIT ? (A1 + (long)bz*sAb) : (const u16*)nullptr;
  const u16* bt = Bt + (long)bz*sBb;
  const int m0 = by*128, n0 = bx*128;
  const int t = threadIdx.x, lane = t & 63, wv = t >> 6;
  const int wm = wv >> 1, wn = wv & 1, r = lane & 15, q = lane >> 4;

  f32x4 acc[4][4] = {};

  auto stage = [&](int buf, int k0){
    #pragma unroll
    for (int h = 0; h < 2; ++h){
      int c = t + h*256;
      int row = c >> 2;
      int qg = (c & 3) ^ ((row >> 1) & 3);   // inverse of read-side swizzle
      int ks = k0 + qg*8;
      const u16* srcA;
      if (SPLIT && ks >= KA0) srcA = a1 + (long)(m0+row)*lda1 + (ks - KA0);
      else                    srcA = a0 + (long)(m0+row)*lda0 + ks;
      gload16(srcA, &As[buf][c*8]);
      gload16(bt + (long)(n0+row)*K + ks, &Bs[buf][c*8]);
    }
  };

  const int nt = K >> 5;
  stage(0, 0);
  __syncthreads();
  for (int it = 0; it < nt; ++it){
    const int cur = it & 1;
    if (it + 1 < nt) stage(cur ^ 1, (it + 1) << 5);   // prefetch overlaps compute
    bf16x8 af[4], bfr[4];
    #pragma unroll
    for (int mi = 0; mi < 4; ++mi){
      int row = wm*64 + mi*16 + r;
      af[mi] = *reinterpret_cast<const bf16x8*>(&As[cur][(row*4 + (q ^ ((row>>1)&3)))*8]);
    }
    #pragma unroll
    for (int ni = 0; ni < 4; ++ni){
      int row = wn*64 + ni*16 + r;
      bfr[ni] = *reinterpret_cast<const bf16x8*>(&Bs[cur][(row*4 + (q ^ ((row>>1)&3)))*8]);
    }
    #pragma unroll
    for (int mi = 0; mi < 4; ++mi)
      #pragma unroll
      for (int ni = 0; ni < 4; ++ni)
        acc[mi][ni] = __builtin_amdgcn_mfma_f32_16x16x32_bf16(af[mi], bfr[ni], acc[mi][ni], 0, 0, 0);
    __syncthreads();   // drains vmcnt (prefetch) + lgkm; one barrier per K-step
  }

  if constexpr (MODE == 2){
    if (t < 128) redbuf[t] = 0.f;
    __syncthreads();
    #pragma unroll
    for (int ni = 0; ni < 4; ++ni){
      float v = 0.f;
      #pragma unroll
      for (int mi = 0; mi < 4; ++mi)
        #pragma unroll
        for (int i = 0; i < 4; ++i) v += fmaxf(acc[mi][ni][i], 0.f);
      v += __shfl_xor(v, 16);
      v += __shfl_xor(v, 32);
      if (q == 0) atomicAdd(&redbuf[wn*64 + ni*16 + r], v);
    }
    __syncthreads();
    float* agg = (float*)Cout;
    if (t < 128) atomicAdd(&agg[(long)(m0 / Lrows)*N + n0 + t], redbuf[t]);
  } else if constexpr (MODE == 3){
    // store att bf16 + masked per-block softmax partial (max, sumexp)
    const int* pmb = pm + bz*512;
    const int* hmb = hm + bz*512;
    int hc[4];
    #pragma unroll
    for (int ni = 0; ni < 4; ++ni) hc[ni] = hmb[n0 + wn*64 + ni*16 + r];
    float tm = -3.0e38f, ts = 0.f;
    #pragma unroll
    for (int mi = 0; mi < 4; ++mi){
      #pragma unroll
      for (int i = 0; i < 4; ++i){
        int rr = m0 + wm*64 + mi*16 + q*4 + i;
        int prm = pmb[rr];
        #pragma unroll
        for (int ni = 0; ni < 4; ++ni){
          float v = acc[mi][ni][i];
          int cc = n0 + wn*64 + ni*16 + r;
          ((u16*)Cout)[(long)bz*sCb + (long)rr*N + cc] = f2b(v);
          float lv = (prm && hc[ni]) ? v : -1.0e9f;
          float nm = fmaxf(tm, lv);
          ts = ts*__expf(tm - nm) + __expf(lv - nm);
          tm = nm;
        }
      }
    }
    #pragma unroll
    for (int d = 1; d < 64; d <<= 1){
      float om = __shfl_xor(tm, d), os = __shfl_xor(ts, d);
      float nm = fmaxf(tm, om);
      ts = ts*__expf(tm - nm) + os*__expf(om - nm);
      tm = nm;
    }
    if (lane == 0) wred4[wv] = float2{tm, ts};
    __syncthreads();
    if (t == 0){
      float m = wred4[0].x, s = wred4[0].y;
      #pragma unroll
      for (int w = 1; w < 4; ++w){
        float om = wred4[w].x, os = wred4[w].y, nm = fmaxf(m, om);
        s = s*__expf(m - nm) + os*__expf(om - nm); m = nm;
      }
      part[bz*16 + by*4 + bx] = float2{m, s};
    }
  } else {
    #pragma unroll
    for (int mi = 0; mi < 4; ++mi){
      #pragma unroll
      for (int ni = 0; ni < 4; ++ni){
        int rr = m0 + wm*64 + mi*16 + q*4;
        int cc = n0 + wn*64 + ni*16 + r;
        #pragma unroll
        for (int i = 0; i < 4; ++i){
          float v = acc[mi][ni][i];
          if (RELU) v = fmaxf(v, 0.f);
          ((u16*)Cout)[(long)bz*sCb + (long)(rr+i)*N + cc] = f2b(v);
        }
      }
    }
  }
}

// ---------------- softmax merge (16 partials per batch) ----------------
__global__ void sm_merge(const float2* __restrict__ part, float2* __restrict__ bms){
  int b = threadIdx.x;   // 128 threads
  float m = -3.0e38f, s = 0.f;
  for (int i = 0; i < 16; ++i){
    float2 p = part[b*16 + i];
    float nm = fmaxf(m, p.x);
    s = s*__expf(m - nm) + p.y*__expf(p.x - nm);
    m = nm;
  }
  bms[b] = float2{m, 1.0f / s};
}

// ---------------- softmax write: bf16 att -> bf16 probs ----------------
__global__ void sm_write_b(const uint4* __restrict__ att, const int* __restrict__ pm,
    const int* __restrict__ hm, const float2* __restrict__ bms, uint4* __restrict__ p2h)
{
  const int total = 128*32768;   // groups of 8 elems
  for (int i = blockIdx.x*blockDim.x + threadIdx.x; i < total; i += gridDim.x*blockDim.x){
    int b = i >> 15, rem = i & 32767, pr = rem >> 6, h0 = (rem & 63) << 3;
    float2 ms = bms[b];
    uint4 v = att[i];
    int pv = pm[b*512 + pr];
    const int* hmb = hm + b*512 + h0;
    const u16* vv = (const u16*)&v;
    u16 o[8];
    #pragma unroll
    for (int j = 0; j < 8; ++j){
      float x = b2f(vv[j]);
      o[j] = (pv && hmb[j]) ? f2b(__expf(x - ms.x)*ms.y) : (u16)0;
    }
    p2h[i] = *(const uint4*)o;
  }
}

// ---------------- fused aggregate FF + scorer + softmax ----------------
__global__ __launch_bounds__(256) void final_ff(const float* __restrict__ aggP,
    const float* __restrict__ aggH, const float* __restrict__ g0,
    const float* __restrict__ g1, const float* __restrict__ sc, float* __restrict__ out)
{
  int b = blockIdx.x, t = threadIdx.x;
  __shared__ float x[1024];
  __shared__ float tt[512];
  __shared__ float2 wred[4];
  for (int i = t; i < 512; i += 256){ x[i] = aggP[b*512 + i]; x[512 + i] = aggH[b*512 + i]; }
  __syncthreads();
  for (int j = t; j < 512; j += 256){
    float a = 0.f;
    for (int k = 0; k < 1024; ++k) a += x[k]*g0[k*512 + j];
    tt[j] = fmaxf(a, 0.f);
  }
  __syncthreads();
  for (int j = t; j < 512; j += 256){
    float a = 0.f;
    for (int k = 0; k < 512; ++k) a += tt[k]*g1[k*512 + j];
    x[j] = fmaxf(a, 0.f);
  }
  __syncthreads();
  float s0 = 0.f, s1 = 0.f;
  for (int k = t; k < 512; k += 256){ s0 += x[k]*sc[2*k]; s1 += x[k]*sc[2*k + 1]; }
  #pragma unroll
  for (int d = 1; d < 64; d <<= 1){ s0 += __shfl_xor(s0, d); s1 += __shfl_xor(s1, d); }
  if ((t & 63) == 0) wred[t >> 6] = float2{s0, s1};
  __syncthreads();
  if (t == 0){
    s0 = wred[0].x + wred[1].x + wred[2].x + wred[3].x;
    s1 = wred[0].y + wred[1].y + wred[2].y + wred[3].y;
    float mm = fmaxf(s0, s1);
    float e0 = __expf(s0 - mm), e1 = __expf(s1 - mm);
    float inv = 1.f / (e0 + e1);
    out[2*b]     = e0*inv;
    out[2*b + 1] = e1*inv;
  }
}

// =============================== launcher ===============================
extern "C" void kernel_launch(void* const* d_in, const int* in_sizes, int n_in,
                              void* d_out, int out_size, void* d_ws, size_t ws_size,
                              hipStream_t stream) {
  const float* premise    = (const float*)d_in[0];
  const float* hypothesis = (const float*)d_in[1];
  const int*   pm         = (const int*)d_in[2];
  const int*   hm         = (const int*)d_in[3];
  const float* w_a0       = (const float*)d_in[4];
  const float* w_a1       = (const float*)d_in[5];
  const float* w_c0       = (const float*)d_in[6];
  const float* w_c1       = (const float*)d_in[7];
  const float* w_g0       = (const float*)d_in[8];
  const float* w_g1       = (const float*)d_in[9];
  const float* w_sc       = (const float*)d_in[10];
  float* out = (float*)d_out;

  const size_t MB = 1ull << 20;
  if (ws_size < 456*MB) return;

  char* ws = (char*)d_ws;
  u16*  p_emb  = (u16*)(ws + 0);
  u16*  h_emb  = (u16*)(ws + 64*MB);
  u16*  bufC   = (u16*)(ws + 128*MB);   // t0 / p2h / cmp_t
  u16*  bufD   = (u16*)(ws + 192*MB);   // proj_p / h2p
  u16*  bufE   = (u16*)(ws + 256*MB);   // proj_h / h_embT / h2p_align
  u16*  att_b  = (u16*)(ws + 320*MB);   // [B,P,H] bf16 (dies after sm_write)
  u16*  p_embT = (u16*)(ws + 320*MB);   // reuses att region after softmax
  u16*  p2h_al = (u16*)(ws + 384*MB);
  u16*  wt_a0  = (u16*)(ws + 448*MB);
  u16*  wt_a1  = (u16*)(ws + 449*MB);
  u16*  wt_c0  = (u16*)(ws + 450*MB);
  u16*  wt_c1  = (u16*)(ws + 452*MB);
  float* aggP  = (float*)(ws + 453*MB);
  float* aggH  = (float*)(ws + 453*MB + 256*1024);
  float2* part = (float2*)(ws + 453*MB + 512*1024);   // 128*16 float2
  float2* bms  = (float2*)(ws + 453*MB + 544*1024);

  const long S = 262144;
  const int NQ = 8388608;
  const float2* nop2 = nullptr;

  // 1. mask + cast to bf16
  mask_cast_k<<<2048, 256, 0, stream>>>((const float4*)premise, pm, (us4*)p_emb, NQ);
  mask_cast_k<<<2048, 256, 0, stream>>>((const float4*)hypothesis, hm, (us4*)h_emb, NQ);

  // 2. weight transposes
  wtrans_k<<<dim3(16,16), 256, 0, stream>>>(w_a0, wt_a0, 512, 512);
  wtrans_k<<<dim3(16,16), 256, 0, stream>>>(w_a1, wt_a1, 512, 512);
  wtrans_k<<<dim3(16,32), 256, 0, stream>>>(w_c0, wt_c0, 1024, 512);
  wtrans_k<<<dim3(16,16), 256, 0, stream>>>(w_c1, wt_c1, 512, 512);

  // 3. attend FF (gy=512 -> gyMask=511, gyShift=9)
  gemm_nt<0,true,false><<<2048, 256, 0, stream>>>(p_emb, nullptr, 0, 512, 0, wt_a0, bufC, nullptr,nullptr,(float2*)nop2, 512, 512, 0,0,0, 0, 511, 9);
  gemm_nt<0,true,false><<<2048, 256, 0, stream>>>(bufC,  nullptr, 0, 512, 0, wt_a1, bufD, nullptr,nullptr,(float2*)nop2, 512, 512, 0,0,0, 0, 511, 9);
  gemm_nt<0,true,false><<<2048, 256, 0, stream>>>(h_emb, nullptr, 0, 512, 0, wt_a0, bufC, nullptr,nullptr,(float2*)nop2, 512, 512, 0,0,0, 0, 511, 9);
  gemm_nt<0,true,false><<<2048, 256, 0, stream>>>(bufC,  nullptr, 0, 512, 0, wt_a1, bufE, nullptr,nullptr,(float2*)nop2, 512, 512, 0,0,0, 0, 511, 9);

  // 4. att = proj_p @ proj_h^T, bf16 store + fused masked softmax partials
  //    batched: gy=4 -> gyMask=3, gyShift=2
  gemm_nt<3,false,false><<<2048, 256, 0, stream>>>(bufD, nullptr, 0, 512, 0, bufE, att_b, pm, hm, part, 512, 512, S, S, S, 0, 3, 2);

  // 5. h_embT for p2h_align GEMM
  btrans_k<<<dim3(8,8,128), 256, 0, stream>>>(h_emb, bufE, 512, 512);

  // 6. softmax merge + write p2h (bf16)
  sm_merge<<<1, 128, 0, stream>>>(part, bms);
  sm_write_b<<<2048, 256, 0, stream>>>((const uint4*)att_b, pm, hm, bms, (uint4*)bufC);

  // 7. h2p = p2h^T; p_embT (att region dead)
  btrans_k<<<dim3(8,8,128), 256, 0, stream>>>(bufC, bufD, 512, 512);
  btrans_k<<<dim3(8,8,128), 256, 0, stream>>>(p_emb, p_embT, 512, 512);

  // 8. alignments
  gemm_nt<0,false,false><<<2048, 256, 0, stream>>>(bufC, nullptr, 0, 512, 0, bufE,   p2h_al, nullptr,nullptr,(float2*)nop2, 512, 512, S, S, S, 0, 3, 2);
  gemm_nt<0,false,false><<<2048, 256, 0, stream>>>(bufD, nullptr, 0, 512, 0, p_embT, bufE,   nullptr,nullptr,(float2*)nop2, 512, 512, S, S, S, 0, 3, 2);

  // 9. compare_p (K=1024 split concat), then layer2 + relu + col-sum
  gemm_nt<0,true,true><<<2048, 256, 0, stream>>>(p_emb, p2h_al, 512, 512, 512, wt_c0, bufC, nullptr,nullptr,(float2*)nop2, 512, 1024, 0,0,0, 0, 511, 9);
  hipMemsetAsync(aggP, 0, 128*512*sizeof(float), stream);
  gemm_nt<2,true,false><<<2048, 256, 0, stream>>>(bufC, nullptr, 0, 512, 0, wt_c1, aggP, nullptr,nullptr,(float2*)nop2, 512, 512, 0,0,0, 512, 511, 9);

  // 10. compare_h
  gemm_nt<0,true,true><<<2048, 256, 0, stream>>>(h_emb, bufE, 512, 512, 512, wt_c0, bufC, nullptr,nullptr,(float2*)nop2, 512, 1024, 0,0,0, 0, 511, 9);
  hipMemsetAsync(aggH, 0, 128*512*sizeof(float), stream);
  gemm_nt<2,true,false><<<2048, 256, 0, stream>>>(bufC, nullptr, 0, 512, 0, wt_c1, aggH, nullptr,nullptr,(float2*)nop2, 512, 512, 0,0,0, 512, 511, 9);

  // 11. aggregate FF + scorer + softmax
  final_ff<<<128, 256, 0, stream>>>(aggP, aggH, w_g0, w_g1, w_sc, out);
}

// Round 3
// 718.245 us; speedup vs baseline: 1.7041x; 1.4874x over previous
//
#include <hip/hip_runtime.h>
#include <hip/hip_bf16.h>
#include <stdint.h>

typedef unsigned short u16;
typedef __bf16 bf16x8 __attribute__((ext_vector_type(8)));
typedef float f32x4 __attribute__((ext_vector_type(4)));

// round-to-nearest-even fp32 -> bf16
__device__ __forceinline__ u16 f2b(float f){
  uint32_t u = __float_as_uint(f);
  u = (u + 0x7fffu + ((u >> 16) & 1u)) >> 16;
  return (u16)u;
}
__device__ __forceinline__ float b2f(u16 u){
  return __uint_as_float(((uint32_t)u) << 16);
}

typedef const void __attribute__((address_space(1))) gv_t;
typedef void __attribute__((address_space(3))) sv_t;

__device__ __forceinline__ void gload16(const void* g, void* l){
  __builtin_amdgcn_global_load_lds((gv_t*)g, (sv_t*)l, 16, 0, 0);
}

// ---------------- per-batch active-row count + exclusive prefix ----------------
// grid 256 (0..127 premise, 128..255 hypothesis), 256 thr
__global__ __launch_bounds__(256) void cnt_scan(const int* __restrict__ pm,
    const int* __restrict__ hm, int* __restrict__ pfx, int* __restrict__ cnts)
{
  int bs = blockIdx.x;
  const int* msk = (bs < 128) ? pm + bs*512 : hm + (bs-128)*512;
  __shared__ int sA[256], sB[256], fl[512];
  int t = threadIdx.x;
  int a = (msk[2*t] != 0), b = (msk[2*t+1] != 0);
  fl[2*t] = a; fl[2*t+1] = b;
  sA[t] = a + b;
  __syncthreads();
  int* cur = sA; int* nxt = sB;
  #pragma unroll
  for (int off = 1; off < 256; off <<= 1){
    int v = cur[t] + ((t >= off) ? cur[t-off] : 0);
    nxt[t] = v;
    __syncthreads();
    int* tmp = cur; cur = nxt; nxt = tmp;
  }
  int incl = cur[t];
  int excl = incl - fl[2*t] - fl[2*t+1];
  pfx[bs*512 + 2*t]     = excl;
  pfx[bs*512 + 2*t + 1] = excl + fl[2*t];
  if (t == 255) cnts[bs] = incl;
}

// ---------------- compact active rows (fp32 -> bf16), zero pads ----------------
// grid 1024: (batch-side bs = blk>>2, quarter = blk&3)
__global__ __launch_bounds__(256) void compact_copy(
    const float* __restrict__ prem, const float* __restrict__ hyp,
    const int* __restrict__ pm, const int* __restrict__ hm,
    const int* __restrict__ pfx, const int* __restrict__ cnts,
    u16* __restrict__ embC)
{
  int blk = blockIdx.x;
  int bs = blk >> 2, qtr = blk & 3;
  const float* src = (bs < 128) ? prem + (long)bs*262144 : hyp + (long)(bs-128)*262144;
  const int*  msk = (bs < 128) ? pm + bs*512 : hm + (bs-128)*512;
  const int*  pf  = pfx + bs*512;
  u16* dstb = embC + (long)bs*262144;
  int t = threadIdx.x;
  for (int idx = t; idx < 128*32; idx += 256){
    int r = qtr*128 + (idx >> 5);
    if (msk[r] == 0) continue;
    int c = (idx & 31) * 16;
    int dr = pf[r];
    const float4* s4 = (const float4*)(src + (long)r*512 + c);
    float4 v0 = s4[0], v1 = s4[1], v2 = s4[2], v3 = s4[3];
    union { u16 o[16]; uint4 q[2]; } u;
    u.o[0]=f2b(v0.x); u.o[1]=f2b(v0.y); u.o[2]=f2b(v0.z); u.o[3]=f2b(v0.w);
    u.o[4]=f2b(v1.x); u.o[5]=f2b(v1.y); u.o[6]=f2b(v1.z); u.o[7]=f2b(v1.w);
    u.o[8]=f2b(v2.x); u.o[9]=f2b(v2.y); u.o[10]=f2b(v2.z); u.o[11]=f2b(v2.w);
    u.o[12]=f2b(v3.x); u.o[13]=f2b(v3.y); u.o[14]=f2b(v3.z); u.o[15]=f2b(v3.w);
    uint4* d4 = (uint4*)(dstb + (long)dr*512 + c);
    d4[0] = u.q[0]; d4[1] = u.q[1];
  }
  // zero pad rows within this quarter's dst range
  int cnt = cnts[bs];
  int lo = qtr*128; if (lo < cnt) lo = cnt;
  int hi = qtr*128 + 128;
  if (hi > lo){
    uint4 z = {0,0,0,0};
    int items = (hi - lo) * 32;
    for (int idx = t; idx < items; idx += 256){
      int r = lo + (idx >> 5);
      int c = (idx & 31) * 16;
      uint4* d4 = (uint4*)(dstb + (long)r*512 + c);
      d4[0] = z; d4[1] = z;
    }
  }
}

// ---------------- weight transposes fp32 [R,C] -> bf16 [C,R] ----------------
__global__ void wtrans3_k(const float* __restrict__ W0, const float* __restrict__ W1,
                          const float* __restrict__ W2, u16* __restrict__ O0,
                          u16* __restrict__ O1, u16* __restrict__ O2){
  __shared__ float tile[32][33];
  const float* W = (blockIdx.z == 0) ? W0 : (blockIdx.z == 1 ? W1 : W2);
  u16* out       = (blockIdx.z == 0) ? O0 : (blockIdx.z == 1 ? O1 : O2);
  int c0 = blockIdx.x*32, r0 = blockIdx.y*32;
  int tx = threadIdx.x & 31, ty = threadIdx.x >> 5;
  #pragma unroll
  for (int i = 0; i < 4; ++i){
    int rr = ty + i*8;
    tile[rr][tx] = W[(long)(r0+rr)*512 + c0 + tx];
  }
  __syncthreads();
  #pragma unroll
  for (int i = 0; i < 4; ++i){
    int rr = ty + i*8;
    out[(long)(c0+rr)*512 + r0 + tx] = f2b(tile[tx][rr]);
  }
}
__global__ void wtrans_k(const float* __restrict__ W, u16* __restrict__ out, int R, int C){
  __shared__ float tile[32][33];
  int c0 = blockIdx.x*32, r0 = blockIdx.y*32;
  int tx = threadIdx.x & 31, ty = threadIdx.x >> 5;
  #pragma unroll
  for (int i = 0; i < 4; ++i){
    int rr = ty + i*8;
    tile[rr][tx] = W[(long)(r0+rr)*C + c0 + tx];
  }
  __syncthreads();
  #pragma unroll
  for (int i = 0; i < 4; ++i){
    int rr = ty + i*8;
    out[(long)(c0+rr)*R + r0 + tx] = f2b(tile[tx][rr]);
  }
}

// ---------------- batched bf16 transpose embC[z] 512x512 -> embT ----------------
// grid (8,8,256): z<128 -> outP (p_embT slot consumer order), z>=128 -> outH
__global__ __launch_bounds__(256) void btrans2(const u16* __restrict__ in,
    u16* __restrict__ outP, u16* __restrict__ outH)
{
  __shared__ u16 tile[64][65];
  int z = blockIdx.z;
  const u16* src = in + (long)z*262144;
  u16* dst = (z < 128) ? outP + (long)z*262144 : outH + (long)(z-128)*262144;
  int c0 = blockIdx.x*64, r0 = blockIdx.y*64;
  int t = threadIdx.x;
  int rr = t >> 3, cc = (t & 7)*8;
  #pragma unroll
  for (int pass = 0; pass < 2; ++pass){
    int r = rr + pass*32;
    uint4 v = *(const uint4*)&src[(long)(r0+r)*512 + c0+cc];
    const u16* vv = (const u16*)&v;
    #pragma unroll
    for (int j = 0; j < 8; ++j) tile[r][cc+j] = vv[j];
  }
  __syncthreads();
  #pragma unroll
  for (int pass = 0; pass < 2; ++pass){
    int r = rr + pass*32;
    union { u16 o[8]; uint4 q; } u;
    #pragma unroll
    for (int j = 0; j < 8; ++j) u.o[j] = tile[cc+j][r];
    *(uint4*)&dst[(long)(c0+r)*512 + r0+cc] = u.q;
  }
}

// ---------------- NT bf16 MFMA GEMM, double-buffered + swizzled + early-exit ----
// C[M,N] = A[M,K] @ Bt[N,K]^T. 128x128 tile, BK=32, 4 waves (2x2).
// 1-D grid nwg (mult of 8), XCD remap l=(p&7)*cpx+(p>>3); bx=l&3, by, bz.
// batchM = (gyMask==3)? bz : by>>2; exit if (by&3)*128 >= cnts[cntMOff+batchM].
// MODE 0: store bf16 (+relu). MODE 2: relu + col-sum atomics into agg[batchM].
// MODE 3: store bf16 + masked softmax partials (mask from cnts), N-exit.
// SPLIT: A = concat[A0 | A1/A1h] along K at KA0 (A1h pre-biased for rows>=65536).
// cntKOff>=0: K truncated to roundup32(cnts[cntKOff+bz]).
template<int MODE, bool RELU, bool SPLIT>
__global__ __launch_bounds__(256) void gemm_nt(
    const u16* __restrict__ A0, const u16* __restrict__ A1, const u16* __restrict__ A1h,
    int KA0, int lda0, int lda1,
    const u16* __restrict__ Bt, void* __restrict__ Cout,
    const int* __restrict__ cnts, int cntMOff, int cntKOff,
    float2* __restrict__ part,
    int N, int K, long sAb, long sBb, long sCb,
    int gyMask, int gyShift, int cpx)
{
  __shared__ u16 As[2][128*32];
  __shared__ u16 Bs[2][128*32];
  __shared__ float redbuf[128];
  __shared__ float2 wred4[4];

  const int p = blockIdx.x;
  const int l = (p & 7)*cpx + (p >> 3);
  const int bx = l & 3;
  const int rest = l >> 2;
  const int by = rest & gyMask;
  const int bz = rest >> gyShift;
  const int batchM = (gyMask == 3) ? bz : (by >> 2);
  const int ml = (by & 3) * 128;
  const int m0 = by*128, n0 = bx*128;
  const int t = threadIdx.x, lane = t & 63, wv = t >> 6;
  const int wm = wv >> 1, wn = wv & 1, r = lane & 15, q = lane >> 4;

  bool dead = (ml >= cnts[cntMOff + batchM]);
  if (MODE == 3 && !dead) dead = (n0 >= cnts[128 + bz]);
  if (dead){
    if (MODE == 3 && t == 0) part[bz*16 + by*4 + bx] = float2{-3.0e38f, 0.f};
    return;
  }

  int Keff = K;
  if (cntKOff >= 0){
    int kc = cnts[cntKOff + bz];
    Keff = (kc + 31) & ~31;
    if (Keff < 32) Keff = 32;
  }
  const int nt = Keff >> 5;

  const u16* a0 = A0 + (long)bz*sAb;
  const u16* a1 = nullptr;
  if (SPLIT) a1 = (m0 < 65536) ? A1 : A1h;
  const u16* bt = Bt + (long)bz*sBb;

  f32x4 acc[4][4] = {};

  auto stage = [&](int buf, int k0){
    #pragma unroll
    for (int h = 0; h < 2; ++h){
      int c = t + h*256;
      int row = c >> 2;
      int qg = (c & 3) ^ ((row >> 1) & 3);   // inverse of read-side swizzle
      int ks = k0 + qg*8;
      const u16* srcA;
      if (SPLIT && ks >= KA0) srcA = a1 + (long)(m0+row)*lda1 + (ks - KA0);
      else                    srcA = a0 + (long)(m0+row)*lda0 + ks;
      gload16(srcA, &As[buf][c*8]);
      gload16(bt + (long)(n0+row)*K + ks, &Bs[buf][c*8]);
    }
  };

  stage(0, 0);
  __syncthreads();
  for (int it = 0; it < nt; ++it){
    const int cur = it & 1;
    if (it + 1 < nt) stage(cur ^ 1, (it + 1) << 5);
    bf16x8 af[4], bfr[4];
    #pragma unroll
    for (int mi = 0; mi < 4; ++mi){
      int row = wm*64 + mi*16 + r;
      af[mi] = *reinterpret_cast<const bf16x8*>(&As[cur][(row*4 + (q ^ ((row>>1)&3)))*8]);
    }
    #pragma unroll
    for (int ni = 0; ni < 4; ++ni){
      int row = wn*64 + ni*16 + r;
      bfr[ni] = *reinterpret_cast<const bf16x8*>(&Bs[cur][(row*4 + (q ^ ((row>>1)&3)))*8]);
    }
    #pragma unroll
    for (int mi = 0; mi < 4; ++mi)
      #pragma unroll
      for (int ni = 0; ni < 4; ++ni)
        acc[mi][ni] = __builtin_amdgcn_mfma_f32_16x16x32_bf16(af[mi], bfr[ni], acc[mi][ni], 0, 0, 0);
    __syncthreads();
  }

  if constexpr (MODE == 2){
    if (t < 128) redbuf[t] = 0.f;
    __syncthreads();
    #pragma unroll
    for (int ni = 0; ni < 4; ++ni){
      float v = 0.f;
      #pragma unroll
      for (int mi = 0; mi < 4; ++mi)
        #pragma unroll
        for (int i = 0; i < 4; ++i) v += fmaxf(acc[mi][ni][i], 0.f);
      v += __shfl_xor(v, 16);
      v += __shfl_xor(v, 32);
      if (q == 0) atomicAdd(&redbuf[wn*64 + ni*16 + r], v);
    }
    __syncthreads();
    float* agg = (float*)Cout;
    if (t < 128) atomicAdd(&agg[(long)batchM*N + n0 + t], redbuf[t]);
  } else if constexpr (MODE == 3){
    const int cp = cnts[bz], ch = cnts[128 + bz];
    int hc[4];
    #pragma unroll
    for (int ni = 0; ni < 4; ++ni) hc[ni] = (n0 + wn*64 + ni*16 + r) < ch;
    float tm = -3.0e38f, ts = 0.f;
    #pragma unroll
    for (int mi = 0; mi < 4; ++mi){
      #pragma unroll
      for (int i = 0; i < 4; ++i){
        int rr = m0 + wm*64 + mi*16 + q*4 + i;
        int prm = rr < cp;
        #pragma unroll
        for (int ni = 0; ni < 4; ++ni){
          float v = acc[mi][ni][i];
          int cc = n0 + wn*64 + ni*16 + r;
          ((u16*)Cout)[(long)bz*sCb + (long)rr*N + cc] = f2b(v);
          float lv = (prm && hc[ni]) ? v : -1.0e9f;
          float nm = fmaxf(tm, lv);
          ts = ts*__expf(tm - nm) + __expf(lv - nm);
          tm = nm;
        }
      }
    }
    #pragma unroll
    for (int d = 1; d < 64; d <<= 1){
      float om = __shfl_xor(tm, d), os = __shfl_xor(ts, d);
      float nm = fmaxf(tm, om);
      ts = ts*__expf(tm - nm) + os*__expf(om - nm);
      tm = nm;
    }
    if (lane == 0) wred4[wv] = float2{tm, ts};
    __syncthreads();
    if (t == 0){
      float m = wred4[0].x, s = wred4[0].y;
      #pragma unroll
      for (int w = 1; w < 4; ++w){
        float om = wred4[w].x, os = wred4[w].y, nm = fmaxf(m, om);
        s = s*__expf(m - nm) + os*__expf(om - nm); m = nm;
      }
      part[bz*16 + by*4 + bx] = float2{m, s};
    }
  } else {
    #pragma unroll
    for (int mi = 0; mi < 4; ++mi){
      #pragma unroll
      for (int ni = 0; ni < 4; ++ni){
        int rr = m0 + wm*64 + mi*16 + q*4;
        int cc = n0 + wn*64 + ni*16 + r;
        #pragma unroll
        for (int i = 0; i < 4; ++i){
          float v = acc[mi][ni][i];
          if (RELU) v = fmaxf(v, 0.f);
          ((u16*)Cout)[(long)bz*sCb + (long)(rr+i)*N + cc] = f2b(v);
        }
      }
    }
  }
}

// ---------------- softmax merge (16 partials per batch) ----------------
__global__ void sm_merge(const float2* __restrict__ part, float2* __restrict__ bms){
  int b = threadIdx.x;   // 128 threads
  float m = -3.0e38f, s = 0.f;
  for (int i = 0; i < 16; ++i){
    float2 p = part[b*16 + i];
    float nm = fmaxf(m, p.x);
    s = s*__expf(m - nm) + p.y*__expf(p.x - nm);
    m = nm;
  }
  bms[b] = float2{m, 1.0f / s};
}

// ---------------- fused softmax-write + transpose: att -> p2h AND h2p ----------
// grid (8,8,128): bx h-tile, by p-tile, bz batch
__global__ __launch_bounds__(256) void sm_write_t(const u16* __restrict__ att,
    const int* __restrict__ cnts, const float2* __restrict__ bms,
    u16* __restrict__ p2h, u16* __restrict__ h2p)
{
  __shared__ u16 tile[64][65];
  int b = blockIdx.z, h0 = blockIdx.x*64, p0 = blockIdx.y*64;
  int cp = cnts[b], ch = cnts[128 + b];
  float2 ms = bms[b];
  int t = threadIdx.x;
  int rr = t >> 3, cc = (t & 7)*8;
  long base = (long)b*262144;
  #pragma unroll
  for (int pass = 0; pass < 2; ++pass){
    int pr = rr + pass*32;
    uint4 v = *(const uint4*)&att[base + (long)(p0+pr)*512 + h0+cc];
    const u16* vv = (const u16*)&v;
    int pa = (p0 + pr) < cp;
    union { u16 o[8]; uint4 q; } u;
    #pragma unroll
    for (int j = 0; j < 8; ++j){
      float x = b2f(vv[j]);
      u.o[j] = (pa && (h0+cc+j) < ch) ? f2b(__expf(x - ms.x)*ms.y) : (u16)0;
    }
    *(uint4*)&p2h[base + (long)(p0+pr)*512 + h0+cc] = u.q;
    #pragma unroll
    for (int j = 0; j < 8; ++j) tile[pr][cc+j] = u.o[j];
  }
  __syncthreads();
  #pragma unroll
  for (int pass = 0; pass < 2; ++pass){
    int hr = rr + pass*32;
    union { u16 o[8]; uint4 q; } u;
    #pragma unroll
    for (int j = 0; j < 8; ++j) u.o[j] = tile[cc+j][hr];
    *(uint4*)&h2p[base + (long)(h0+hr)*512 + p0+cc] = u.q;
  }
}

// ---------------- fused aggregate FF + scorer + softmax ----------------
__global__ __launch_bounds__(256) void final_ff(const float* __restrict__ agg,
    const float* __restrict__ g0, const float* __restrict__ g1,
    const float* __restrict__ sc, float* __restrict__ out)
{
  int b = blockIdx.x, t = threadIdx.x;
  __shared__ float x[1024];
  __shared__ float tt[512];
  __shared__ float2 wred[4];
  for (int i = t; i < 512; i += 256){
    x[i]       = agg[(long)b*512 + i];
    x[512 + i] = agg[(long)(128 + b)*512 + i];
  }
  __syncthreads();
  for (int j = t; j < 512; j += 256){
    float a = 0.f;
    for (int k = 0; k < 1024; ++k) a += x[k]*g0[k*512 + j];
    tt[j] = fmaxf(a, 0.f);
  }
  __syncthreads();
  for (int j = t; j < 512; j += 256){
    float a = 0.f;
    for (int k = 0; k < 512; ++k) a += tt[k]*g1[k*512 + j];
    x[j] = fmaxf(a, 0.f);
  }
  __syncthreads();
  float s0 = 0.f, s1 = 0.f;
  for (int k = t; k < 512; k += 256){ s0 += x[k]*sc[2*k]; s1 += x[k]*sc[2*k + 1]; }
  #pragma unroll
  for (int d = 1; d < 64; d <<= 1){ s0 += __shfl_xor(s0, d); s1 += __shfl_xor(s1, d); }
  if ((t & 63) == 0) wred[t >> 6] = float2{s0, s1};
  __syncthreads();
  if (t == 0){
    s0 = wred[0].x + wred[1].x + wred[2].x + wred[3].x;
    s1 = wred[0].y + wred[1].y + wred[2].y + wred[3].y;
    float mm = fmaxf(s0, s1);
    float e0 = __expf(s0 - mm), e1 = __expf(s1 - mm);
    float inv = 1.f / (e0 + e1);
    out[2*b]     = e0*inv;
    out[2*b + 1] = e1*inv;
  }
}

// =============================== launcher ===============================
extern "C" void kernel_launch(void* const* d_in, const int* in_sizes, int n_in,
                              void* d_out, int out_size, void* d_ws, size_t ws_size,
                              hipStream_t stream) {
  const float* premise    = (const float*)d_in[0];
  const float* hypothesis = (const float*)d_in[1];
  const int*   pm         = (const int*)d_in[2];
  const int*   hm         = (const int*)d_in[3];
  const float* w_a0       = (const float*)d_in[4];
  const float* w_a1       = (const float*)d_in[5];
  const float* w_c0       = (const float*)d_in[6];
  const float* w_c1       = (const float*)d_in[7];
  const float* w_g0       = (const float*)d_in[8];
  const float* w_g1       = (const float*)d_in[9];
  const float* w_sc       = (const float*)d_in[10];
  float* out = (float*)d_out;

  const size_t MB = 1ull << 20;
  if (ws_size < 456*MB) return;

  char* ws = (char*)d_ws;
  // [0,128): embC (compacted p rows then h rows, [256][512][512] bf16)
  u16* embC    = (u16*)(ws + 0);
  // [128,256): t0 pair -> embT pair (h_embT@128, p_embT@192) -> align_h@128, cmp_t@[192,320)
  u16* t0      = (u16*)(ws + 128*MB);
  u16* h_embT  = (u16*)(ws + 128*MB);
  u16* align_h = (u16*)(ws + 128*MB);
  u16* p_embT  = (u16*)(ws + 192*MB);
  u16* cmp_t   = (u16*)(ws + 192*MB);
  // [256,384): proj pair -> p2h@256, h2p@320
  u16* proj    = (u16*)(ws + 256*MB);
  u16* p2h     = (u16*)(ws + 256*MB);
  u16* h2p     = (u16*)(ws + 320*MB);
  // [384,448): att_b -> align_p
  u16* att_b   = (u16*)(ws + 384*MB);
  u16* align_p = (u16*)(ws + 384*MB);
  // weights + small
  u16*  wt_a0  = (u16*)(ws + 448*MB);
  u16*  wt_a1  = (u16*)(ws + 449*MB);
  u16*  wt_c0  = (u16*)(ws + 450*MB);
  u16*  wt_c1  = (u16*)(ws + 452*MB);
  float* agg   = (float*)(ws + 453*MB);                 // [256][512]
  int*   pfx   = (int*)(ws + 453*MB + 512*1024);        // [256][512]
  int*   cnts  = (int*)(ws + 454*MB);                   // [256]
  float2* part = (float2*)(ws + 454*MB + 4096);         // [128][16]
  float2* bms  = (float2*)(ws + 454*MB + 24*1024);      // [128]

  const long S = 262144;
  u16* projP = proj;
  u16* projH = proj + (long)128*S;

  // 1. counts/prefix + compaction (mask+cast+compact, zero pads)
  cnt_scan<<<256, 256, 0, stream>>>(pm, hm, pfx, cnts);
  compact_copy<<<1024, 256, 0, stream>>>(premise, hypothesis, pm, hm, pfx, cnts, embC);

  // 2. weight transposes
  wtrans3_k<<<dim3(16,16,3), 256, 0, stream>>>(w_a0, w_a1, w_c1, wt_a0, wt_a1, wt_c1);
  wtrans_k<<<dim3(16,32), 256, 0, stream>>>(w_c0, wt_c0, 1024, 512);
  hipMemsetAsync(agg, 0, 256*512*sizeof(float), stream);

  // 3. attend FF, p+h merged (M=131072): nwg=4096, gyMask=1023, gyShift=10, cpx=512
  gemm_nt<0,true,false><<<4096, 256, 0, stream>>>(embC, nullptr, nullptr, 0, 512, 0,
      wt_a0, t0, cnts, 0, -1, nullptr, 512, 512, 0, 0, 0, 1023, 10, 512);
  gemm_nt<0,true,false><<<4096, 256, 0, stream>>>(t0, nullptr, nullptr, 0, 512, 0,
      wt_a1, proj, cnts, 0, -1, nullptr, 512, 512, 0, 0, 0, 1023, 10, 512);

  // 4. embT pair (t0 dead): h_embT@128 (from h side), p_embT@192 (from p side)
  btrans2<<<dim3(8,8,256), 256, 0, stream>>>(embC, p_embT, h_embT);

  // 5. att = proj_p @ proj_h^T (bf16) + fused masked softmax partials
  gemm_nt<3,false,false><<<2048, 256, 0, stream>>>(projP, nullptr, nullptr, 0, 512, 0,
      projH, att_b, cnts, 0, -1, part, 512, 512, S, S, S, 3, 2, 256);

  // 6. softmax merge + fused write p2h / h2p (proj dead -> [256,384) reused)
  sm_merge<<<1, 128, 0, stream>>>(part, bms);
  sm_write_t<<<dim3(8,8,128), 256, 0, stream>>>(att_b, cnts, bms, p2h, h2p);

  // 7. alignments (K truncated to active count); att dead -> align_p@384
  gemm_nt<0,false,false><<<2048, 256, 0, stream>>>(p2h, nullptr, nullptr, 0, 512, 0,
      h_embT, align_p, cnts, 0, 128, nullptr, 512, 512, S, S, S, 3, 2, 256);
  // h_embT dead -> align_h@128
  gemm_nt<0,false,false><<<2048, 256, 0, stream>>>(h2p, nullptr, nullptr, 0, 512, 0,
      p_embT, align_h, cnts, 128, 0, nullptr, 512, 512, S, S, S, 3, 2, 256);

  // 8. compare l1 (K=1024 split concat), p+h merged; p_embT/p2h/h2p dead -> cmp_t@[192,320)
  gemm_nt<0,true,true><<<4096, 256, 0, stream>>>(embC, align_p, align_h - (long)65536*512,
      512, 512, 512, wt_c0, cmp_t, cnts, 0, -1, nullptr, 512, 1024, 0, 0, 0, 1023, 10, 512);

  // 9. compare l2 + relu + column-sum into agg[256][512]
  gemm_nt<2,true,false><<<4096, 256, 0, stream>>>(cmp_t, nullptr, nullptr, 0, 512, 0,
      wt_c1, agg, cnts, 0, -1, nullptr, 512, 512, 0, 0, 0, 1023, 10, 512);

  // 10. aggregate FF + scorer + 2-class softmax
  final_ff<<<128, 256, 0, stream>>>(agg, w_g0, w_g1, w_sc, out);
}